// Round 1
// 364.636 us; speedup vs baseline: 1.0923x; 1.0923x over previous
//
#include <hip/hip_runtime.h>
#include <cstdint>
#include <cstddef>

#define NE 16
#define TOPK 6
#define HID 1024
#define NTOK 8192
#define EPSF 1e-10f
#define CAP_ROWS 51200   // Y capacity: 400 * 128 (worst-case 128-padded rows)
#define MAXB256 208      // worst-case 256-row mblocks: (400+16)/2
#define NT 16            // K tiles of 64 (1024/64)

typedef short bf16x8 __attribute__((ext_vector_type(8)));
typedef float f32x4 __attribute__((ext_vector_type(4)));

__device__ __forceinline__ unsigned int f2bf_rne(float f) {
  union { float f; unsigned int u; } v;
  v.f = f;
  return (v.u + 0x7FFFu + ((v.u >> 16) & 1u)) >> 16;
}

__device__ __forceinline__ float bfbits2f(unsigned int hi16) {
  union { unsigned int u; float f; } v;
  v.u = hi16 << 16;
  return v.f;
}

__device__ __forceinline__ void load_lds16(const void* g, void* l) {
  __builtin_amdgcn_global_load_lds(
      (const __attribute__((address_space(1))) void*)g,
      (__attribute__((address_space(3))) void*)l, 16, 0, 0);
}

// router: logits -> softmax -> top6. All lanes redundantly compute top-k;
// fuses X f32->bf16. gate_k = q_k/s_top; eps = EPS*s/(s+EPS).
__global__ __launch_bounds__(256) void router_sparse_kernel(
    const float* __restrict__ tokens, const float* __restrict__ rw,
    const float* __restrict__ rb, unsigned short* __restrict__ Xb,
    unsigned int* __restrict__ topk, float* __restrict__ g6,
    float* __restrict__ epst) {
  __shared__ float s_rw[NE * HID];
  const int tid = threadIdx.x;
  const int wv = tid >> 6;
  const int lane = tid & 63;
  const int token = blockIdx.x * 4 + wv;

  for (int i = tid; i < NE * HID / 4; i += 256)
    ((float4*)s_rw)[i] = ((const float4*)rw)[i];
  __syncthreads();

  const float* xp = tokens + (size_t)token * HID;
  float x[16];
#pragma unroll
  for (int j = 0; j < 16; ++j) x[j] = xp[lane + 64 * j];

  unsigned short* xbrow = Xb + (size_t)token * HID;
#pragma unroll
  for (int j = 0; j < 16; ++j)
    xbrow[lane + 64 * j] = (unsigned short)f2bf_rne(x[j]);

  float lg[NE];
#pragma unroll
  for (int e = 0; e < NE; ++e) {
    const float* w = s_rw + e * HID;
    float p = 0.f;
#pragma unroll
    for (int j = 0; j < 16; ++j) p += x[j] * w[lane + 64 * j];
    lg[e] = p;
  }
#pragma unroll
  for (int m = 1; m < 64; m <<= 1) {
#pragma unroll
    for (int e = 0; e < NE; ++e) lg[e] += __shfl_xor(lg[e], m);
  }
  float mx = -1e30f;
#pragma unroll
  for (int e = 0; e < NE; ++e) {
    lg[e] += rb[e];
    mx = fmaxf(mx, lg[e]);
  }
  float q[NE];
  float s_all = 0.f;
#pragma unroll
  for (int e = 0; e < NE; ++e) {
    q[e] = expf(lg[e] - mx);
    s_all += q[e];
  }
  unsigned sel = 0, pack = 0;
  float s_top = 0.f;
  float gq[TOPK];
#pragma unroll
  for (int k = 0; k < TOPK; ++k) {
    float best = -1.f;
    int bi = 0;
#pragma unroll
    for (int e = 0; e < NE; ++e) {
      bool taken = (sel >> e) & 1u;
      if (!taken && q[e] > best) { best = q[e]; bi = e; }
    }
    sel |= 1u << bi;
    gq[k] = best;
    s_top += best;
    pack |= ((unsigned)bi) << (4 * k);
  }
  if (lane < TOPK)
    g6[(size_t)token * TOPK + lane] = gq[lane] / s_top;
  if (lane == 32) {
    topk[token] = pack;
    float s = s_top / s_all;
    epst[token] = EPSF * (s / (s + EPSF));
  }
}

// fused prep: blocks [0,16) = sortassign (hist+scan+scatter+pad+256-table);
// blocks [16, 16+4096) = W f32 [e][k][n] -> bf16 transposed [e][n][k].
// Fusing hides the 16-block sort under the 4096-block convert.
__global__ __launch_bounds__(256) void prep_kernel(
    const float* __restrict__ ew, unsigned short* __restrict__ wt,
    const unsigned int* __restrict__ topk, const float* __restrict__ g6,
    unsigned int* __restrict__ tokmap, float* __restrict__ gpos,
    unsigned int* __restrict__ inv, unsigned int* __restrict__ table,
    unsigned int* __restrict__ total) {
  __shared__ float tile[64][65];
  __shared__ unsigned int hist[NE];
  __shared__ unsigned int s_seg[NE];
  __shared__ unsigned int s_sc[256];
  const int tid = threadIdx.x;

  if (blockIdx.x >= NE) {
    // ---- cvt_wt body ----
    const int q = blockIdx.x - NE;
    const int e2 = q >> 8;
    const int ntile = ((q >> 4) & 15) * 64;
    const int ktile = (q & 15) * 64;
    const int tr = tid >> 6;
    const int tc = tid & 63;
    const float* wp = ew + (size_t)e2 * HID * HID;
#pragma unroll
    for (int r = 0; r < 64; r += 4)
      tile[r + tr][tc] = wp[(size_t)(ktile + r + tr) * HID + ntile + tc];
    __syncthreads();
    unsigned short* wo = wt + (size_t)e2 * HID * HID;
    const int aa = tid & 31;   // k-pair index
    const int rg = tid >> 5;   // row-in-group 0..7
#pragma unroll
    for (int c2 = 0; c2 < 64; c2 += 8) {
      const int n = c2 + rg;
      const unsigned lo = f2bf_rne(tile[2 * aa][n]);
      const unsigned hi = f2bf_rne(tile[2 * aa + 1][n]);
      *(unsigned int*)(wo + (size_t)(ntile + n) * HID + ktile + 2 * aa) =
          lo | (hi << 16);
    }
    return;
  }

  // ---- sortassign body ----
  const int e = blockIdx.x;

  if (tid < NE) hist[tid] = 0;
  __syncthreads();
  for (int t = tid; t < NTOK; t += 256) {
    const unsigned p = topk[t];
#pragma unroll
    for (int k = 0; k < TOPK; ++k) atomicAdd(&hist[(p >> (4 * k)) & 15u], 1u);
  }
  __syncthreads();
  if (tid == 0) {
    unsigned off = 0;
    for (int i = 0; i < NE; ++i) {
      s_seg[i] = off;
      off += ((hist[i] + 127) >> 7) << 7;
    }
  }
  __syncthreads();
  if (e == 0 && tid == 0) {
    // 256-row mblock table: pair 128-mblocks; odd leftover -> HALF flag (bit 23)
    unsigned b = 0;
    for (int i = 0; i < NE; ++i) {
      const unsigned nb = (hist[i] + 127) >> 7;
      const unsigned seg = s_seg[i];
      unsigned m = 0;
      for (; m + 2 <= nb; m += 2)
        table[b++] = ((unsigned)i << 24) | (seg + m * 128);
      if (m < nb)
        table[b++] = ((unsigned)i << 24) | (1u << 23) | (seg + m * 128);
    }
    *total = b;
  }

  const int tbase = tid * (NTOK / 256);
  unsigned c = 0;
  for (int i = 0; i < NTOK / 256; ++i) {
    const unsigned p = topk[tbase + i];
#pragma unroll
    for (int k = 0; k < TOPK; ++k) c += (((p >> (4 * k)) & 15u) == (unsigned)e);
  }
  s_sc[tid] = c;
  __syncthreads();
  for (int off = 1; off < 256; off <<= 1) {
    unsigned v = (tid >= off) ? s_sc[tid - off] : 0u;
    __syncthreads();
    s_sc[tid] += v;
    __syncthreads();
  }
  const unsigned seg0 = s_seg[e];
  unsigned pos = seg0 + s_sc[tid] - c;
  for (int i = 0; i < NTOK / 256; ++i) {
    const int t = tbase + i;
    const unsigned p = topk[t];
#pragma unroll
    for (int k = 0; k < TOPK; ++k) {
      if (((p >> (4 * k)) & 15u) == (unsigned)e) {
        tokmap[pos] = (unsigned)t;
        gpos[pos] = g6[(size_t)t * TOPK + k];
        inv[(size_t)t * TOPK + k] = pos;
        ++pos;
      }
    }
  }
  const unsigned cnt_e = s_sc[255];
  const unsigned segend = seg0 + (((cnt_e + 127) >> 7) << 7);
  for (unsigned p2 = seg0 + cnt_e + tid; p2 < segend; p2 += 256) {
    tokmap[p2] = 0u;
    gpos[p2] = 0.f;
  }
}

// grouped GEMM, 256x256 tile, BK=64, 8 waves (2Mx4N), double-buffered LDS,
// 8-phase-style schedule: per K-tile 4 phases of {ds_read subtile || 2x
// global_load_lds prefetch || barrier || lgkmcnt(0) || setprio(1)+16 MFMA ||
// barrier}, counted vmcnt (4/2) gates -- loads stay in flight across barriers.
// LDS XOR swizzle (row&7 on 16B slot) applied via pre-swizzled GLOBAL source
// (global_load_lds writes linearly) + matching XOR on ds_read address.
__global__ __launch_bounds__(512, 2) void moe_ggemm_kernel(
    const unsigned short* __restrict__ Xb, const unsigned short* __restrict__ Wt,
    const unsigned int* __restrict__ table, const unsigned int* __restrict__ total,
    const unsigned int* __restrict__ tokmap, const float* __restrict__ gpos,
    unsigned short* __restrict__ Y) {
  __shared__ unsigned short As[2][256][64];  // 64 KiB
  __shared__ unsigned short Bs[2][256][64];  // 64 KiB
  __shared__ unsigned int Ts[256];
  __shared__ float Gs[256];

  const unsigned tot = *total;
  const unsigned bx = blockIdx.x;
  // bijective XCD chunk swizzle: 832 = 8 * 104; XCD x owns 104 contiguous wgs
  const unsigned wg = (bx & 7u) * (MAXB256 * 4u / 8u) + (bx >> 3);
  const unsigned slot = wg >> 2;
  if (slot >= tot) return;
  const int n0 = (int)(wg & 3u) * 256;
  const unsigned ent = table[slot];
  const int e = (int)(ent >> 24);
  const int half = (int)((ent >> 23) & 1u);
  const int row0 = (int)(ent & 0x7FFFFFu);

  const int tid = threadIdx.x;
  const int wv = tid >> 6;
  const int lane = tid & 63;
  const int lm = lane & 15;
  const int quad = lane >> 4;
  const int wvm = wv >> 2;            // 0..1
  const int woff_m = wvm * 128;
  const int woff_n = (wv & 3) * 64;

  if (tid < 256) {
    const int rc = (half && tid >= 128) ? 127 : tid;
    Ts[tid] = tokmap[row0 + rc];
    Gs[tid] = (half && tid >= 128) ? 0.f : gpos[row0 + rc];
  }
  __syncthreads();

  // staging: instr i covers tile rows [i*64, i*64+64); thread -> (row, 16B slot)
  const int srow = tid >> 3;                          // 0..63
  const int scol = ((tid & 7) ^ (srow & 7)) << 4;     // pre-swizzled source col
  const char* pA[4];
  const char* pB[4];
#pragma unroll
  for (int i = 0; i < 4; ++i) {
    pA[i] = (const char*)Xb + (size_t)Ts[i * 64 + srow] * (HID * 2) + scol;
    pB[i] = (const char*)Wt + (size_t)e * (HID * HID * 2) +
            (size_t)(n0 + i * 64 + srow) * (HID * 2) + scol;
  }
  char* const Ab = (char*)&As[0][0][0];
  char* const Bb = (char*)&Bs[0][0][0];
  const int sdst = wv * 8 * 128;  // wave-uniform lane0 dest within 8KB instr block

  // prologue: stage tile 0 -> buf0, order A0,A2,B0,B1,B2,B3,A1,A3
  load_lds16(pA[0], Ab + 0 * 8192 + sdst);
  load_lds16(pA[2], Ab + 2 * 8192 + sdst);
  load_lds16(pB[0], Bb + 0 * 8192 + sdst);
  load_lds16(pB[1], Bb + 1 * 8192 + sdst);
  load_lds16(pB[2], Bb + 2 * 8192 + sdst);
  load_lds16(pB[3], Bb + 3 * 8192 + sdst);
  load_lds16(pA[1], Ab + 1 * 8192 + sdst);
  load_lds16(pA[3], Ab + 3 * 8192 + sdst);

  f32x4 acc[8][4];
#pragma unroll
  for (int f = 0; f < 8; ++f)
#pragma unroll
    for (int g = 0; g < 4; ++g) acc[f][g] = (f32x4){0.f, 0.f, 0.f, 0.f};

  const int rsw = (lm & 7) << 4;              // read-side unswizzle XOR
  const int roff0 = (quad * 16) ^ rsw;        // ks=0
  const int roff1 = (64 + quad * 16) ^ rsw;   // ks=1

  // gate: first 6 (A0,A2,B0..B3) of tile0 done; A1,A3 may stay in flight
  asm volatile("s_waitcnt vmcnt(2)" ::: "memory");
  __builtin_amdgcn_s_barrier();

  for (int kt = 0; kt < NT; ++kt) {
    const int c = kt & 1;
    const int koff = (kt < NT - 1 ? kt + 1 : kt) * 128;  // clamp: restage last
    const char* ab = Ab + c * 32768;
    const char* bb = Bb + c * 32768;
    char* const ast = Ab + (c ^ 1) * 32768;
    char* const bst = Bb + (c ^ 1) * 32768;

    bf16x8 a[4][2], b[4][2];

    // -------- P0: read a(f0-3), b(g0-1); stage next A0,A2
#pragma unroll
    for (int f = 0; f < 4; ++f) {
      const char* rp = ab + (woff_m + 16 * f + lm) * 128;
      a[f][0] = *(const bf16x8*)(rp + roff0);
      a[f][1] = *(const bf16x8*)(rp + roff1);
    }
#pragma unroll
    for (int g = 0; g < 2; ++g) {
      const char* rp = bb + (woff_n + 16 * g + lm) * 128;
      b[g][0] = *(const bf16x8*)(rp + roff0);
      b[g][1] = *(const bf16x8*)(rp + roff1);
    }
    load_lds16(pA[0] + koff, ast + 0 * 8192 + sdst);
    load_lds16(pA[2] + koff, ast + 2 * 8192 + sdst);
    __builtin_amdgcn_s_barrier();
    asm volatile("s_waitcnt lgkmcnt(0)" ::: "memory");
    __builtin_amdgcn_s_setprio(1);
#pragma unroll
    for (int f = 0; f < 4; ++f)
#pragma unroll
      for (int g = 0; g < 2; ++g) {
        acc[f][g] = __builtin_amdgcn_mfma_f32_16x16x32_bf16(a[f][0], b[g][0], acc[f][g], 0, 0, 0);
        acc[f][g] = __builtin_amdgcn_mfma_f32_16x16x32_bf16(a[f][1], b[g][1], acc[f][g], 0, 0, 0);
      }
    __builtin_amdgcn_s_setprio(0);
    __builtin_amdgcn_s_barrier();

    // -------- P1: read b(g2-3); stage next B0,B1; gate vmcnt(4)
#pragma unroll
    for (int g = 2; g < 4; ++g) {
      const char* rp = bb + (woff_n + 16 * g + lm) * 128;
      b[g][0] = *(const bf16x8*)(rp + roff0);
      b[g][1] = *(const bf16x8*)(rp + roff1);
    }
    load_lds16(pB[0] + koff, bst + 0 * 8192 + sdst);
    load_lds16(pB[1] + koff, bst + 1 * 8192 + sdst);
    __builtin_amdgcn_s_barrier();
    asm volatile("s_waitcnt lgkmcnt(0)" ::: "memory");
    __builtin_amdgcn_s_setprio(1);
#pragma unroll
    for (int f = 0; f < 4; ++f)
#pragma unroll
      for (int g = 2; g < 4; ++g) {
        acc[f][g] = __builtin_amdgcn_mfma_f32_16x16x32_bf16(a[f][0], b[g][0], acc[f][g], 0, 0, 0);
        acc[f][g] = __builtin_amdgcn_mfma_f32_16x16x32_bf16(a[f][1], b[g][1], acc[f][g], 0, 0, 0);
      }
    __builtin_amdgcn_s_setprio(0);
    // outstanding: A1,A3(cur) + A0,A2,B0,B1(next) -> wait cur A1,A3 for P2
    asm volatile("s_waitcnt vmcnt(4)" ::: "memory");
    __builtin_amdgcn_s_barrier();

    // -------- P2: read a(f4-7) into a[0-3]; stage next B2,B3
#pragma unroll
    for (int f = 0; f < 4; ++f) {
      const char* rp = ab + (woff_m + 16 * (f + 4) + lm) * 128;
      a[f][0] = *(const bf16x8*)(rp + roff0);
      a[f][1] = *(const bf16x8*)(rp + roff1);
    }
    load_lds16(pB[2] + koff, bst + 2 * 8192 + sdst);
    load_lds16(pB[3] + koff, bst + 3 * 8192 + sdst);
    __builtin_amdgcn_s_barrier();
    asm volatile("s_waitcnt lgkmcnt(0)" ::: "memory");
    __builtin_amdgcn_s_setprio(1);
#pragma unroll
    for (int f = 0; f < 4; ++f)
#pragma unroll
      for (int g = 2; g < 4; ++g) {
        acc[f + 4][g] = __builtin_amdgcn_mfma_f32_16x16x32_bf16(a[f][0], b[g][0], acc[f + 4][g], 0, 0, 0);
        acc[f + 4][g] = __builtin_amdgcn_mfma_f32_16x16x32_bf16(a[f][1], b[g][1], acc[f + 4][g], 0, 0, 0);
      }
    __builtin_amdgcn_s_setprio(0);
    __builtin_amdgcn_s_barrier();

    // -------- P3: stage next A1,A3; mfma f4-7 x g0-1 (b0-1 kept live); gate vmcnt(2)
    load_lds16(pA[1] + koff, ast + 1 * 8192 + sdst);
    load_lds16(pA[3] + koff, ast + 3 * 8192 + sdst);
    __builtin_amdgcn_s_barrier();
    __builtin_amdgcn_s_setprio(1);
#pragma unroll
    for (int f = 0; f < 4; ++f)
#pragma unroll
      for (int g = 0; g < 2; ++g) {
        acc[f + 4][g] = __builtin_amdgcn_mfma_f32_16x16x32_bf16(a[f][0], b[g][0], acc[f + 4][g], 0, 0, 0);
        acc[f + 4][g] = __builtin_amdgcn_mfma_f32_16x16x32_bf16(a[f][1], b[g][1], acc[f + 4][g], 0, 0, 0);
      }
    __builtin_amdgcn_s_setprio(0);
    // outstanding: next-tile A0,A2,B0..B3,A1,A3 -> wait first 6 for next P0
    asm volatile("s_waitcnt vmcnt(2)" ::: "memory");
    __builtin_amdgcn_s_barrier();
  }

  // drain dangling (restaged) loads before LDS goes away / epilogue
  asm volatile("s_waitcnt vmcnt(0)" ::: "memory");

  if (!(half && wvm)) {
#pragma unroll
    for (int f = 0; f < 8; ++f)
#pragma unroll
      for (int r = 0; r < 4; ++r) {
        const int row = woff_m + 16 * f + quad * 4 + r;
        const float gte = Gs[row];
        unsigned short* yrow = Y + (size_t)(row0 + row) * HID + n0;
#pragma unroll
        for (int g = 0; g < 4; ++g)
          yrow[woff_n + 16 * g + lm] = (unsigned short)f2bf_rne(gte * acc[f][g][r]);
      }
  }
}

// reduce: out[t,:] = sum_k Y[inv[t,k],:] + eps[t].  2 tokens/block.
__global__ __launch_bounds__(256) void reduce_kernel(
    const unsigned short* __restrict__ Y, const unsigned int* __restrict__ inv,
    const float* __restrict__ epst, float* __restrict__ out) {
  const int sub = threadIdx.x >> 7;
  const int ct = threadIdx.x & 127;
  const int t = blockIdx.x * 2 + sub;
  const int c0 = ct * 8;

  float s[8];
  const float ep = epst[t];
#pragma unroll
  for (int i = 0; i < 8; ++i) s[i] = ep;

#pragma unroll
  for (int k = 0; k < TOPK; ++k) {
    const unsigned pos = inv[(size_t)t * TOPK + k];
    const uint4 v = *(const uint4*)(Y + (size_t)pos * HID + c0);
    s[0] += bfbits2f(v.x & 0xFFFFu);
    s[1] += bfbits2f(v.x >> 16);
    s[2] += bfbits2f(v.y & 0xFFFFu);
    s[3] += bfbits2f(v.y >> 16);
    s[4] += bfbits2f(v.z & 0xFFFFu);
    s[5] += bfbits2f(v.z >> 16);
    s[6] += bfbits2f(v.w & 0xFFFFu);
    s[7] += bfbits2f(v.w >> 16);
  }
  float* orow = out + (size_t)t * HID + c0;
  *(float4*)orow = (float4){s[0], s[1], s[2], s[3]};
  *(float4*)(orow + 4) = (float4){s[4], s[5], s[6], s[7]};
}

extern "C" void kernel_launch(void* const* d_in, const int* in_sizes, int n_in,
                              void* d_out, int out_size, void* d_ws, size_t ws_size,
                              hipStream_t stream) {
  const float* tokens = (const float*)d_in[0];  // [4,2048,1024] f32
  const float* rw = (const float*)d_in[1];      // [16,1024] f32
  const float* rb = (const float*)d_in[2];      // [16] f32
  const float* ew = (const float*)d_in[3];      // [16,1024,1024] f32
  float* out = (float*)d_out;                   // [4,2048,1024] f32

  char* ws = (char*)d_ws;
  const size_t OFF_XB = 0;                        // 16 MB
  const size_t OFF_WT = 16777216;                 // 32 MB
  const size_t OFF_Y = 50331648;                  // 100 MB (51200 x 1024 bf16)
  const size_t OFF_META = 155189248;
  const size_t M_TOKMAP = OFF_META + 0;           // 51200 u32
  const size_t M_GPOS = OFF_META + 204800;        // 51200 f32
  const size_t M_TOTAL = OFF_META + 409600;       // 1 u32 (pad 64)
  const size_t M_TABLE = OFF_META + 409664;       // 400 u32 (pad)
  const size_t M_INV = OFF_META + 411328;         // 49152 u32
  const size_t M_TOPK = OFF_META + 607936;        // 8192 u32
  const size_t M_G6 = OFF_META + 640704;          // 49152 f32
  const size_t M_EPST = OFF_META + 837312;        // 8192 f32

  unsigned short* Xb = (unsigned short*)(ws + OFF_XB);
  unsigned short* Wt = (unsigned short*)(ws + OFF_WT);
  unsigned short* Y = (unsigned short*)(ws + OFF_Y);
  unsigned int* tokmap = (unsigned int*)(ws + M_TOKMAP);
  float* gpos = (float*)(ws + M_GPOS);
  unsigned int* total = (unsigned int*)(ws + M_TOTAL);
  unsigned int* table = (unsigned int*)(ws + M_TABLE);
  unsigned int* inv = (unsigned int*)(ws + M_INV);
  unsigned int* topk = (unsigned int*)(ws + M_TOPK);
  float* g6 = (float*)(ws + M_G6);
  float* epst = (float*)(ws + M_EPST);

  router_sparse_kernel<<<dim3(NTOK / 4), dim3(256), 0, stream>>>(
      tokens, rw, rb, Xb, topk, g6, epst);
  prep_kernel<<<dim3(NE + (HID / 64) * (HID / 64) * NE), dim3(256), 0, stream>>>(
      ew, Wt, topk, g6, tokmap, gpos, inv, table, total);
  moe_ggemm_kernel<<<dim3(MAXB256 * 4), dim3(512), 0, stream>>>(
      Xb, Wt, table, total, tokmap, gpos, Y);
  reduce_kernel<<<dim3(NTOK / 2), dim3(256), 0, stream>>>(Y, inv, epst, out);
}

// Round 2
// 343.135 us; speedup vs baseline: 1.1608x; 1.0627x over previous
//
#include <hip/hip_runtime.h>
#include <cstdint>
#include <cstddef>

#define NE 16
#define TOPK 6
#define HID 1024
#define NTOK 8192
#define EPSF 1e-10f
#define CAP_ROWS 51200   // Y capacity: 400 * 128 (worst-case 128-padded rows)
#define MAXB256 208      // worst-case 256-row mblocks: (400+16)/2
#define NT 16            // K tiles of 64 (1024/64)
#define ROUTER_BLKS 2048 // NTOK/4

typedef short bf16x8 __attribute__((ext_vector_type(8)));
typedef float f32x4 __attribute__((ext_vector_type(4)));

__device__ __forceinline__ unsigned int f2bf_rne(float f) {
  union { float f; unsigned int u; } v;
  v.f = f;
  return (v.u + 0x7FFFu + ((v.u >> 16) & 1u)) >> 16;
}

__device__ __forceinline__ float bfbits2f(unsigned int hi16) {
  union { unsigned int u; float f; } v;
  v.u = hi16 << 16;
  return v.f;
}

__device__ __forceinline__ void load_lds16(const void* g, void* l) {
  __builtin_amdgcn_global_load_lds(
      (const __attribute__((address_space(1))) void*)g,
      (__attribute__((address_space(3))) void*)l, 16, 0, 0);
}

// fused independent pre-work:
//   blocks [0, ROUTER_BLKS): router (LDS-free; rw read direct, L2-hot) -
//     logits -> softmax -> top6; fuses X f32->bf16 conversion.
//   blocks [ROUTER_BLKS, +4096): W f32 [e][k][n] -> bf16 transposed [e][n][k].
// Router no longer uses 64KB LDS staging (was 2 blocks/CU occupancy cap and
// 128MB redundant staging traffic); both halves run at ~8 blocks/CU.
__global__ __launch_bounds__(256) void fused_pre_kernel(
    const float* __restrict__ tokens, const float* __restrict__ rw,
    const float* __restrict__ rb, unsigned short* __restrict__ Xb,
    unsigned int* __restrict__ topk, float* __restrict__ g6,
    float* __restrict__ epst, const float* __restrict__ ew,
    unsigned short* __restrict__ wt) {
  __shared__ float tile[64][65];
  const int tid = threadIdx.x;
  const unsigned bx = blockIdx.x;

  if (bx >= ROUTER_BLKS) {
    // ---- cvt_wt body ----
    const int q = bx - ROUTER_BLKS;
    const int e2 = q >> 8;
    const int ntile = ((q >> 4) & 15) * 64;
    const int ktile = (q & 15) * 64;
    const int tr = tid >> 6;
    const int tc = tid & 63;
    const float* wp = ew + (size_t)e2 * HID * HID;
#pragma unroll
    for (int r = 0; r < 64; r += 4)
      tile[r + tr][tc] = wp[(size_t)(ktile + r + tr) * HID + ntile + tc];
    __syncthreads();
    unsigned short* wo = wt + (size_t)e2 * HID * HID;
    const int aa = tid & 31;   // k-pair index
    const int rg = tid >> 5;   // row-in-group 0..7
#pragma unroll
    for (int c2 = 0; c2 < 64; c2 += 8) {
      const int n = c2 + rg;
      const unsigned lo = f2bf_rne(tile[2 * aa][n]);
      const unsigned hi = f2bf_rne(tile[2 * aa + 1][n]);
      *(unsigned int*)(wo + (size_t)(ntile + n) * HID + ktile + 2 * aa) =
          lo | (hi << 16);
    }
    return;
  }

  // ---- router body ----
  const int wv = tid >> 6;
  const int lane = tid & 63;
  const int token = (int)bx * 4 + wv;

  const float4* xp4 = (const float4*)(tokens + (size_t)token * HID);
  float4 x4[4];
#pragma unroll
  for (int j = 0; j < 4; ++j) x4[j] = xp4[lane + 64 * j];

  unsigned short* xbrow = Xb + (size_t)token * HID;
#pragma unroll
  for (int j = 0; j < 4; ++j) {
    const unsigned lo = f2bf_rne(x4[j].x) | (f2bf_rne(x4[j].y) << 16);
    const unsigned hi = f2bf_rne(x4[j].z) | (f2bf_rne(x4[j].w) << 16);
    *(uint2*)(xbrow + 4 * (lane + 64 * j)) = (uint2){lo, hi};
  }

  float lg[NE];
#pragma unroll
  for (int e = 0; e < NE; ++e) {
    const float4* wp4 = (const float4*)(rw + e * HID);
    float p = 0.f;
#pragma unroll
    for (int j = 0; j < 4; ++j) {
      const float4 w = wp4[lane + 64 * j];
      p += x4[j].x * w.x + x4[j].y * w.y + x4[j].z * w.z + x4[j].w * w.w;
    }
    lg[e] = p;
  }
#pragma unroll
  for (int m = 1; m < 64; m <<= 1) {
#pragma unroll
    for (int e = 0; e < NE; ++e) lg[e] += __shfl_xor(lg[e], m);
  }
  float mx = -1e30f;
#pragma unroll
  for (int e = 0; e < NE; ++e) {
    lg[e] += rb[e];
    mx = fmaxf(mx, lg[e]);
  }
  float q[NE];
  float s_all = 0.f;
#pragma unroll
  for (int e = 0; e < NE; ++e) {
    q[e] = expf(lg[e] - mx);
    s_all += q[e];
  }
  unsigned sel = 0, pack = 0;
  float s_top = 0.f;
  float gq[TOPK];
#pragma unroll
  for (int k = 0; k < TOPK; ++k) {
    float best = -1.f;
    int bi = 0;
#pragma unroll
    for (int e = 0; e < NE; ++e) {
      bool taken = (sel >> e) & 1u;
      if (!taken && q[e] > best) { best = q[e]; bi = e; }
    }
    sel |= 1u << bi;
    gq[k] = best;
    s_top += best;
    pack |= ((unsigned)bi) << (4 * k);
  }
  if (lane < TOPK)
    g6[(size_t)token * TOPK + lane] = gq[lane] / s_top;
  if (lane == 32) {
    topk[token] = pack;
    float s = s_top / s_all;
    epst[token] = EPSF * (s / (s + EPSF));
  }
}

// sortassign, atomic-free: 16 blocks x 1024 threads.
// hist: thread (hx=tid&15, hc=tid>>4) counts expert hx (wave-uniform compare,
// no runtime-indexed reg arrays) over a 128-token chunk; LDS tree reduce.
// Then Hillis-Steele rank scan (8 tokens/thread) + scatter + pad fill.
// Block 0 also emits the 256-row mblock table (pair 128s; odd -> HALF bit 23).
__global__ __launch_bounds__(1024) void sortassign_kernel(
    const unsigned int* __restrict__ topk, const float* __restrict__ g6,
    unsigned int* __restrict__ tokmap, float* __restrict__ gpos,
    unsigned int* __restrict__ inv, unsigned int* __restrict__ table,
    unsigned int* __restrict__ total) {
  __shared__ unsigned int sred[NE][65];
  __shared__ unsigned int s_seg[NE];
  __shared__ unsigned int hist[NE];
  __shared__ unsigned int s_sc[1024];
  const int e = blockIdx.x;
  const int tid = threadIdx.x;

  {
    const unsigned hx = tid & 15u;
    const int hc = tid >> 4;
    const unsigned int* tp = topk + hc * 128;
    unsigned hcnt = 0;
    for (int i = 0; i < 128; ++i) {
      const unsigned p = tp[i];
#pragma unroll
      for (int k = 0; k < TOPK; ++k) hcnt += (((p >> (4 * k)) & 15u) == hx);
    }
    sred[hx][hc] = hcnt;
  }
  __syncthreads();
  if (tid < NE) {
    unsigned s = 0;
    for (int j = 0; j < 64; ++j) s += sred[tid][j];
    hist[tid] = s;
  }
  __syncthreads();
  if (tid == 0) {
    unsigned off = 0;
    for (int i = 0; i < NE; ++i) {
      s_seg[i] = off;
      off += ((hist[i] + 127) >> 7) << 7;
    }
  }
  __syncthreads();
  if (e == 0 && tid == 0) {
    unsigned b = 0;
    for (int i = 0; i < NE; ++i) {
      const unsigned nb = (hist[i] + 127) >> 7;
      const unsigned seg = s_seg[i];
      unsigned m = 0;
      for (; m + 2 <= nb; m += 2)
        table[b++] = ((unsigned)i << 24) | (seg + m * 128);
      if (m < nb)
        table[b++] = ((unsigned)i << 24) | (1u << 23) | (seg + m * 128);
    }
    *total = b;
  }

  const int tbase = tid * (NTOK / 1024);  // 8 tokens/thread
  unsigned c = 0;
  for (int i = 0; i < NTOK / 1024; ++i) {
    const unsigned p = topk[tbase + i];
#pragma unroll
    for (int k = 0; k < TOPK; ++k) c += (((p >> (4 * k)) & 15u) == (unsigned)e);
  }
  s_sc[tid] = c;
  __syncthreads();
  for (int off = 1; off < 1024; off <<= 1) {
    unsigned v = (tid >= off) ? s_sc[tid - off] : 0u;
    __syncthreads();
    s_sc[tid] += v;
    __syncthreads();
  }
  const unsigned seg0 = s_seg[e];
  unsigned pos = seg0 + s_sc[tid] - c;
  for (int i = 0; i < NTOK / 1024; ++i) {
    const int t = tbase + i;
    const unsigned p = topk[t];
#pragma unroll
    for (int k = 0; k < TOPK; ++k) {
      if (((p >> (4 * k)) & 15u) == (unsigned)e) {
        tokmap[pos] = (unsigned)t;
        gpos[pos] = g6[(size_t)t * TOPK + k];
        inv[(size_t)t * TOPK + k] = pos;
        ++pos;
      }
    }
  }
  const unsigned cnt_e = s_sc[1023];
  const unsigned segend = seg0 + (((cnt_e + 127) >> 7) << 7);
  for (unsigned p2 = seg0 + cnt_e + tid; p2 < segend; p2 += 1024) {
    tokmap[p2] = 0u;
    gpos[p2] = 0.f;
  }
}

// grouped GEMM, 256x256 tile, BK=64, 8 waves (2Mx4N), double-buffered LDS,
// 8-phase-style schedule with counted vmcnt gates; LDS XOR swizzle via
// pre-swizzled global source + matching XOR on ds_read. (verified round 1:
// bank conflicts 0, FETCH 94.5MB)
__global__ __launch_bounds__(512, 2) void moe_ggemm_kernel(
    const unsigned short* __restrict__ Xb, const unsigned short* __restrict__ Wt,
    const unsigned int* __restrict__ table, const unsigned int* __restrict__ total,
    const unsigned int* __restrict__ tokmap, const float* __restrict__ gpos,
    unsigned short* __restrict__ Y) {
  __shared__ unsigned short As[2][256][64];  // 64 KiB
  __shared__ unsigned short Bs[2][256][64];  // 64 KiB
  __shared__ unsigned int Ts[256];
  __shared__ float Gs[256];

  const unsigned tot = *total;
  const unsigned bx = blockIdx.x;
  // bijective XCD chunk swizzle: 832 = 8 * 104
  const unsigned wg = (bx & 7u) * (MAXB256 * 4u / 8u) + (bx >> 3);
  const unsigned slot = wg >> 2;
  if (slot >= tot) return;
  const int n0 = (int)(wg & 3u) * 256;
  const unsigned ent = table[slot];
  const int e = (int)(ent >> 24);
  const int half = (int)((ent >> 23) & 1u);
  const int row0 = (int)(ent & 0x7FFFFFu);

  const int tid = threadIdx.x;
  const int wv = tid >> 6;
  const int lane = tid & 63;
  const int lm = lane & 15;
  const int quad = lane >> 4;
  const int wvm = wv >> 2;            // 0..1
  const int woff_m = wvm * 128;
  const int woff_n = (wv & 3) * 64;

  if (tid < 256) {
    const int rc = (half && tid >= 128) ? 127 : tid;
    Ts[tid] = tokmap[row0 + rc];
    Gs[tid] = (half && tid >= 128) ? 0.f : gpos[row0 + rc];
  }
  __syncthreads();

  const int srow = tid >> 3;                          // 0..63
  const int scol = ((tid & 7) ^ (srow & 7)) << 4;     // pre-swizzled source col
  const char* pA[4];
  const char* pB[4];
#pragma unroll
  for (int i = 0; i < 4; ++i) {
    pA[i] = (const char*)Xb + (size_t)Ts[i * 64 + srow] * (HID * 2) + scol;
    pB[i] = (const char*)Wt + (size_t)e * (HID * HID * 2) +
            (size_t)(n0 + i * 64 + srow) * (HID * 2) + scol;
  }
  char* const Ab = (char*)&As[0][0][0];
  char* const Bb = (char*)&Bs[0][0][0];
  const int sdst = wv * 8 * 128;

  load_lds16(pA[0], Ab + 0 * 8192 + sdst);
  load_lds16(pA[2], Ab + 2 * 8192 + sdst);
  load_lds16(pB[0], Bb + 0 * 8192 + sdst);
  load_lds16(pB[1], Bb + 1 * 8192 + sdst);
  load_lds16(pB[2], Bb + 2 * 8192 + sdst);
  load_lds16(pB[3], Bb + 3 * 8192 + sdst);
  load_lds16(pA[1], Ab + 1 * 8192 + sdst);
  load_lds16(pA[3], Ab + 3 * 8192 + sdst);

  f32x4 acc[8][4];
#pragma unroll
  for (int f = 0; f < 8; ++f)
#pragma unroll
    for (int g = 0; g < 4; ++g) acc[f][g] = (f32x4){0.f, 0.f, 0.f, 0.f};

  const int rsw = (lm & 7) << 4;
  const int roff0 = (quad * 16) ^ rsw;
  const int roff1 = (64 + quad * 16) ^ rsw;

  asm volatile("s_waitcnt vmcnt(2)" ::: "memory");
  __builtin_amdgcn_s_barrier();

  for (int kt = 0; kt < NT; ++kt) {
    const int c = kt & 1;
    const int koff = (kt < NT - 1 ? kt + 1 : kt) * 128;
    const char* ab = Ab + c * 32768;
    const char* bb = Bb + c * 32768;
    char* const ast = Ab + (c ^ 1) * 32768;
    char* const bst = Bb + (c ^ 1) * 32768;

    bf16x8 a[4][2], b[4][2];

    // P0
#pragma unroll
    for (int f = 0; f < 4; ++f) {
      const char* rp = ab + (woff_m + 16 * f + lm) * 128;
      a[f][0] = *(const bf16x8*)(rp + roff0);
      a[f][1] = *(const bf16x8*)(rp + roff1);
    }
#pragma unroll
    for (int g = 0; g < 2; ++g) {
      const char* rp = bb + (woff_n + 16 * g + lm) * 128;
      b[g][0] = *(const bf16x8*)(rp + roff0);
      b[g][1] = *(const bf16x8*)(rp + roff1);
    }
    load_lds16(pA[0] + koff, ast + 0 * 8192 + sdst);
    load_lds16(pA[2] + koff, ast + 2 * 8192 + sdst);
    __builtin_amdgcn_s_barrier();
    asm volatile("s_waitcnt lgkmcnt(0)" ::: "memory");
    __builtin_amdgcn_s_setprio(1);
#pragma unroll
    for (int f = 0; f < 4; ++f)
#pragma unroll
      for (int g = 0; g < 2; ++g) {
        acc[f][g] = __builtin_amdgcn_mfma_f32_16x16x32_bf16(a[f][0], b[g][0], acc[f][g], 0, 0, 0);
        acc[f][g] = __builtin_amdgcn_mfma_f32_16x16x32_bf16(a[f][1], b[g][1], acc[f][g], 0, 0, 0);
      }
    __builtin_amdgcn_s_setprio(0);
    __builtin_amdgcn_s_barrier();

    // P1
#pragma unroll
    for (int g = 2; g < 4; ++g) {
      const char* rp = bb + (woff_n + 16 * g + lm) * 128;
      b[g][0] = *(const bf16x8*)(rp + roff0);
      b[g][1] = *(const bf16x8*)(rp + roff1);
    }
    load_lds16(pB[0] + koff, bst + 0 * 8192 + sdst);
    load_lds16(pB[1] + koff, bst + 1 * 8192 + sdst);
    __builtin_amdgcn_s_barrier();
    asm volatile("s_waitcnt lgkmcnt(0)" ::: "memory");
    __builtin_amdgcn_s_setprio(1);
#pragma unroll
    for (int f = 0; f < 4; ++f)
#pragma unroll
      for (int g = 2; g < 4; ++g) {
        acc[f][g] = __builtin_amdgcn_mfma_f32_16x16x32_bf16(a[f][0], b[g][0], acc[f][g], 0, 0, 0);
        acc[f][g] = __builtin_amdgcn_mfma_f32_16x16x32_bf16(a[f][1], b[g][1], acc[f][g], 0, 0, 0);
      }
    __builtin_amdgcn_s_setprio(0);
    asm volatile("s_waitcnt vmcnt(4)" ::: "memory");
    __builtin_amdgcn_s_barrier();

    // P2
#pragma unroll
    for (int f = 0; f < 4; ++f) {
      const char* rp = ab + (woff_m + 16 * (f + 4) + lm) * 128;
      a[f][0] = *(const bf16x8*)(rp + roff0);
      a[f][1] = *(const bf16x8*)(rp + roff1);
    }
    load_lds16(pB[2] + koff, bst + 2 * 8192 + sdst);
    load_lds16(pB[3] + koff, bst + 3 * 8192 + sdst);
    __builtin_amdgcn_s_barrier();
    asm volatile("s_waitcnt lgkmcnt(0)" ::: "memory");
    __builtin_amdgcn_s_setprio(1);
#pragma unroll
    for (int f = 0; f < 4; ++f)
#pragma unroll
      for (int g = 2; g < 4; ++g) {
        acc[f + 4][g] = __builtin_amdgcn_mfma_f32_16x16x32_bf16(a[f][0], b[g][0], acc[f + 4][g], 0, 0, 0);
        acc[f + 4][g] = __builtin_amdgcn_mfma_f32_16x16x32_bf16(a[f][1], b[g][1], acc[f + 4][g], 0, 0, 0);
      }
    __builtin_amdgcn_s_setprio(0);
    __builtin_amdgcn_s_barrier();

    // P3
    load_lds16(pA[1] + koff, ast + 1 * 8192 + sdst);
    load_lds16(pA[3] + koff, ast + 3 * 8192 + sdst);
    __builtin_amdgcn_s_barrier();
    __builtin_amdgcn_s_setprio(1);
#pragma unroll
    for (int f = 0; f < 4; ++f)
#pragma unroll
      for (int g = 0; g < 2; ++g) {
        acc[f + 4][g] = __builtin_amdgcn_mfma_f32_16x16x32_bf16(a[f][0], b[g][0], acc[f + 4][g], 0, 0, 0);
        acc[f + 4][g] = __builtin_amdgcn_mfma_f32_16x16x32_bf16(a[f][1], b[g][1], acc[f + 4][g], 0, 0, 0);
      }
    __builtin_amdgcn_s_setprio(0);
    asm volatile("s_waitcnt vmcnt(2)" ::: "memory");
    __builtin_amdgcn_s_barrier();
  }

  asm volatile("s_waitcnt vmcnt(0)" ::: "memory");

  if (!(half && wvm)) {
#pragma unroll
    for (int f = 0; f < 8; ++f)
#pragma unroll
      for (int r = 0; r < 4; ++r) {
        const int row = woff_m + 16 * f + quad * 4 + r;
        const float gte = Gs[row];
        unsigned short* yrow = Y + (size_t)(row0 + row) * HID + n0;
#pragma unroll
        for (int g = 0; g < 4; ++g)
          yrow[woff_n + 16 * g + lm] = (unsigned short)f2bf_rne(gte * acc[f][g][r]);
      }
  }
}

// reduce: out[t,:] = sum_k Y[inv[t,k],:] + eps[t].  2 tokens/block.
__global__ __launch_bounds__(256) void reduce_kernel(
    const unsigned short* __restrict__ Y, const unsigned int* __restrict__ inv,
    const float* __restrict__ epst, float* __restrict__ out) {
  const int sub = threadIdx.x >> 7;
  const int ct = threadIdx.x & 127;
  const int t = blockIdx.x * 2 + sub;
  const int c0 = ct * 8;

  float s[8];
  const float ep = epst[t];
#pragma unroll
  for (int i = 0; i < 8; ++i) s[i] = ep;

#pragma unroll
  for (int k = 0; k < TOPK; ++k) {
    const unsigned pos = inv[(size_t)t * TOPK + k];
    const uint4 v = *(const uint4*)(Y + (size_t)pos * HID + c0);
    s[0] += bfbits2f(v.x & 0xFFFFu);
    s[1] += bfbits2f(v.x >> 16);
    s[2] += bfbits2f(v.y & 0xFFFFu);
    s[3] += bfbits2f(v.y >> 16);
    s[4] += bfbits2f(v.z & 0xFFFFu);
    s[5] += bfbits2f(v.z >> 16);
    s[6] += bfbits2f(v.w & 0xFFFFu);
    s[7] += bfbits2f(v.w >> 16);
  }
  float* orow = out + (size_t)t * HID + c0;
  *(float4*)orow = (float4){s[0], s[1], s[2], s[3]};
  *(float4*)(orow + 4) = (float4){s[4], s[5], s[6], s[7]};
}

extern "C" void kernel_launch(void* const* d_in, const int* in_sizes, int n_in,
                              void* d_out, int out_size, void* d_ws, size_t ws_size,
                              hipStream_t stream) {
  const float* tokens = (const float*)d_in[0];  // [4,2048,1024] f32
  const float* rw = (const float*)d_in[1];      // [16,1024] f32
  const float* rb = (const float*)d_in[2];      // [16] f32
  const float* ew = (const float*)d_in[3];      // [16,1024,1024] f32
  float* out = (float*)d_out;                   // [4,2048,1024] f32

  char* ws = (char*)d_ws;
  const size_t OFF_XB = 0;                        // 16 MB
  const size_t OFF_WT = 16777216;                 // 32 MB
  const size_t OFF_Y = 50331648;                  // 100 MB (51200 x 1024 bf16)
  const size_t OFF_META = 155189248;
  const size_t M_TOKMAP = OFF_META + 0;           // 51200 u32
  const size_t M_GPOS = OFF_META + 204800;        // 51200 f32
  const size_t M_TOTAL = OFF_META + 409600;       // 1 u32 (pad 64)
  const size_t M_TABLE = OFF_META + 409664;       // 400 u32 (pad)
  const size_t M_INV = OFF_META + 411328;         // 49152 u32
  const size_t M_TOPK = OFF_META + 607936;        // 8192 u32
  const size_t M_G6 = OFF_META + 640704;          // 49152 f32
  const size_t M_EPST = OFF_META + 837312;        // 8192 f32

  unsigned short* Xb = (unsigned short*)(ws + OFF_XB);
  unsigned short* Wt = (unsigned short*)(ws + OFF_WT);
  unsigned short* Y = (unsigned short*)(ws + OFF_Y);
  unsigned int* tokmap = (unsigned int*)(ws + M_TOKMAP);
  float* gpos = (float*)(ws + M_GPOS);
  unsigned int* total = (unsigned int*)(ws + M_TOTAL);
  unsigned int* table = (unsigned int*)(ws + M_TABLE);
  unsigned int* inv = (unsigned int*)(ws + M_INV);
  unsigned int* topk = (unsigned int*)(ws + M_TOPK);
  float* g6 = (float*)(ws + M_G6);
  float* epst = (float*)(ws + M_EPST);

  fused_pre_kernel<<<dim3(ROUTER_BLKS + (HID / 64) * (HID / 64) * NE), dim3(256),
                     0, stream>>>(tokens, rw, rb, Xb, topk, g6, epst, ew, Wt);
  sortassign_kernel<<<dim3(NE), dim3(1024), 0, stream>>>(
      topk, g6, tokmap, gpos, inv, table, total);
  moe_ggemm_kernel<<<dim3(MAXB256 * 4), dim3(512), 0, stream>>>(
      Xb, Wt, table, total, tokmap, gpos, Y);
  reduce_kernel<<<dim3(NTOK / 2), dim3(256), 0, stream>>>(Y, inv, epst, out);
}

// Round 3
// 340.656 us; speedup vs baseline: 1.1692x; 1.0073x over previous
//
#include <hip/hip_runtime.h>
#include <cstdint>
#include <cstddef>

#define NE 16
#define TOPK 6
#define HID 1024
#define NTOK 8192
#define EPSF 1e-10f
#define CAP_ROWS 51200   // Y capacity: 400 * 128 (worst-case 128-padded rows)
#define MAXB256 208      // worst-case 256-row mblocks: (400+16)/2
#define NT 16            // K tiles of 64 (1024/64)
#define ROUTER_BLKS 2048 // NTOK/4

typedef short bf16x8 __attribute__((ext_vector_type(8)));
typedef float f32x4 __attribute__((ext_vector_type(4)));

__device__ __forceinline__ unsigned int f2bf_rne(float f) {
  union { float f; unsigned int u; } v;
  v.f = f;
  return (v.u + 0x7FFFu + ((v.u >> 16) & 1u)) >> 16;
}

__device__ __forceinline__ float bfbits2f(unsigned int hi16) {
  union { unsigned int u; float f; } v;
  v.u = hi16 << 16;
  return v.f;
}

__device__ __forceinline__ void load_lds16(const void* g, void* l) {
  __builtin_amdgcn_global_load_lds(
      (const __attribute__((address_space(1))) void*)g,
      (__attribute__((address_space(3))) void*)l, 16, 0, 0);
}

// fused independent pre-work:
//   blocks [0, ROUTER_BLKS): router (LDS-free; rw read direct, L2-hot) -
//     logits -> softmax -> top6; fuses X f32->bf16 conversion.
//   blocks [ROUTER_BLKS, +4096): W f32 [e][k][n] -> bf16 transposed [e][n][k].
__global__ __launch_bounds__(256) void fused_pre_kernel(
    const float* __restrict__ tokens, const float* __restrict__ rw,
    const float* __restrict__ rb, unsigned short* __restrict__ Xb,
    unsigned int* __restrict__ topk, float* __restrict__ g6,
    float* __restrict__ epst, const float* __restrict__ ew,
    unsigned short* __restrict__ wt) {
  __shared__ float tile[64][65];
  const int tid = threadIdx.x;
  const unsigned bx = blockIdx.x;

  if (bx >= ROUTER_BLKS) {
    // ---- cvt_wt body ----
    const int q = bx - ROUTER_BLKS;
    const int e2 = q >> 8;
    const int ntile = ((q >> 4) & 15) * 64;
    const int ktile = (q & 15) * 64;
    const int tr = tid >> 6;
    const int tc = tid & 63;
    const float* wp = ew + (size_t)e2 * HID * HID;
#pragma unroll
    for (int r = 0; r < 64; r += 4)
      tile[r + tr][tc] = wp[(size_t)(ktile + r + tr) * HID + ntile + tc];
    __syncthreads();
    unsigned short* wo = wt + (size_t)e2 * HID * HID;
    const int aa = tid & 31;   // k-pair index
    const int rg = tid >> 5;   // row-in-group 0..7
#pragma unroll
    for (int c2 = 0; c2 < 64; c2 += 8) {
      const int n = c2 + rg;
      const unsigned lo = f2bf_rne(tile[2 * aa][n]);
      const unsigned hi = f2bf_rne(tile[2 * aa + 1][n]);
      *(unsigned int*)(wo + (size_t)(ntile + n) * HID + ktile + 2 * aa) =
          lo | (hi << 16);
    }
    return;
  }

  // ---- router body ----
  const int wv = tid >> 6;
  const int lane = tid & 63;
  const int token = (int)bx * 4 + wv;

  const float4* xp4 = (const float4*)(tokens + (size_t)token * HID);
  float4 x4[4];
#pragma unroll
  for (int j = 0; j < 4; ++j) x4[j] = xp4[lane + 64 * j];

  unsigned short* xbrow = Xb + (size_t)token * HID;
#pragma unroll
  for (int j = 0; j < 4; ++j) {
    const unsigned lo = f2bf_rne(x4[j].x) | (f2bf_rne(x4[j].y) << 16);
    const unsigned hi = f2bf_rne(x4[j].z) | (f2bf_rne(x4[j].w) << 16);
    *(uint2*)(xbrow + 4 * (lane + 64 * j)) = (uint2){lo, hi};
  }

  float lg[NE];
#pragma unroll
  for (int e = 0; e < NE; ++e) {
    const float4* wp4 = (const float4*)(rw + e * HID);
    float p = 0.f;
#pragma unroll
    for (int j = 0; j < 4; ++j) {
      const float4 w = wp4[lane + 64 * j];
      p += x4[j].x * w.x + x4[j].y * w.y + x4[j].z * w.z + x4[j].w * w.w;
    }
    lg[e] = p;
  }
#pragma unroll
  for (int m = 1; m < 64; m <<= 1) {
#pragma unroll
    for (int e = 0; e < NE; ++e) lg[e] += __shfl_xor(lg[e], m);
  }
  float mx = -1e30f;
#pragma unroll
  for (int e = 0; e < NE; ++e) {
    lg[e] += rb[e];
    mx = fmaxf(mx, lg[e]);
  }
  float q[NE];
  float s_all = 0.f;
#pragma unroll
  for (int e = 0; e < NE; ++e) {
    q[e] = expf(lg[e] - mx);
    s_all += q[e];
  }
  unsigned sel = 0, pack = 0;
  float s_top = 0.f;
  float gq[TOPK];
#pragma unroll
  for (int k = 0; k < TOPK; ++k) {
    float best = -1.f;
    int bi = 0;
#pragma unroll
    for (int e = 0; e < NE; ++e) {
      bool taken = (sel >> e) & 1u;
      if (!taken && q[e] > best) { best = q[e]; bi = e; }
    }
    sel |= 1u << bi;
    gq[k] = best;
    s_top += best;
    pack |= ((unsigned)bi) << (4 * k);
  }
  if (lane < TOPK)
    g6[(size_t)token * TOPK + lane] = gq[lane] / s_top;
  if (lane == 32) {
    topk[token] = pack;
    float s = s_top / s_all;
    epst[token] = EPSF * (s / (s + EPSF));
  }
}

// sortassign, atomic-free, 4 barriers (was 22: Hillis-Steele -> shfl wave scan).
// 16 blocks x 1024 threads. hist via per-thread uniform-expert counts + LDS
// tree reduce; rank via wave-level __shfl_up scan + tid0 cross-wave scan.
__global__ __launch_bounds__(1024) void sortassign_kernel(
    const unsigned int* __restrict__ topk, const float* __restrict__ g6,
    unsigned int* __restrict__ tokmap, float* __restrict__ gpos,
    unsigned int* __restrict__ inv, unsigned int* __restrict__ table,
    unsigned int* __restrict__ total) {
  __shared__ unsigned int sred[NE][65];
  __shared__ unsigned int s_seg[NE];
  __shared__ unsigned int hist[NE];
  __shared__ unsigned int wofs[16];
  const int e = blockIdx.x;
  const int tid = threadIdx.x;
  const int lane = tid & 63;
  const int wvid = tid >> 6;

  // full 16-expert histogram (needed for segment offsets on every block)
  {
    const unsigned hx = tid & 15u;
    const int hc = tid >> 4;
    const unsigned int* tp = topk + hc * 128;
    unsigned hcnt = 0;
    for (int i = 0; i < 128; ++i) {
      const unsigned p = tp[i];
#pragma unroll
      for (int k = 0; k < TOPK; ++k) hcnt += (((p >> (4 * k)) & 15u) == hx);
    }
    sred[hx][hc] = hcnt;
  }
  __syncthreads();
  if (tid < NE) {
    unsigned s = 0;
    for (int jj = 0; jj < 64; ++jj) s += sred[tid][jj];
    hist[tid] = s;
  }
  __syncthreads();
  if (tid == 0) {
    unsigned off = 0;
    for (int i = 0; i < NE; ++i) {
      s_seg[i] = off;
      off += ((hist[i] + 127) >> 7) << 7;
    }
    if (e == 0) {
      // 256-row mblock table: pair 128-mblocks; odd leftover -> HALF bit 23
      unsigned b = 0;
      for (int i = 0; i < NE; ++i) {
        const unsigned nb = (hist[i] + 127) >> 7;
        const unsigned seg = s_seg[i];
        unsigned m = 0;
        for (; m + 2 <= nb; m += 2)
          table[b++] = ((unsigned)i << 24) | (seg + m * 128);
        if (m < nb)
          table[b++] = ((unsigned)i << 24) | (1u << 23) | (seg + m * 128);
      }
      *total = b;
    }
  }

  // per-thread count of expert e over its 8-token chunk
  const int tbase = tid * (NTOK / 1024);
  unsigned c = 0;
  for (int i = 0; i < NTOK / 1024; ++i) {
    const unsigned p = topk[tbase + i];
#pragma unroll
    for (int k = 0; k < TOPK; ++k) c += (((p >> (4 * k)) & 15u) == (unsigned)e);
  }
  // wave inclusive scan
  unsigned pfx = c;
#pragma unroll
  for (int m = 1; m < 64; m <<= 1) {
    const unsigned v = __shfl_up(pfx, m);
    if (lane >= m) pfx += v;
  }
  if (lane == 63) wofs[wvid] = pfx;
  __syncthreads();  // also makes s_seg visible
  if (tid == 0) {
    unsigned r = 0;
    for (int i = 0; i < 16; ++i) { const unsigned t = wofs[i]; wofs[i] = r; r += t; }
  }
  __syncthreads();

  const unsigned seg0 = s_seg[e];
  unsigned pos = seg0 + wofs[wvid] + (pfx - c);
  for (int i = 0; i < NTOK / 1024; ++i) {
    const int t = tbase + i;
    const unsigned p = topk[t];
#pragma unroll
    for (int k = 0; k < TOPK; ++k) {
      if (((p >> (4 * k)) & 15u) == (unsigned)e) {
        tokmap[pos] = (unsigned)t;
        gpos[pos] = g6[(size_t)t * TOPK + k];
        inv[(size_t)t * TOPK + k] = pos;
        ++pos;
      }
    }
  }
  const unsigned cnt_e = hist[e];
  const unsigned segend = seg0 + (((cnt_e + 127) >> 7) << 7);
  for (unsigned p2 = seg0 + cnt_e + tid; p2 < segend; p2 += 1024) {
    tokmap[p2] = 0u;
    gpos[p2] = 0.f;
  }
}

// PERSISTENT grouped GEMM: grid = 256 blocks (1/CU), XCD-chunked wg lists.
// 256x256 tile, BK=64, 8 waves (2Mx4N), dbuf LDS, 8-phase counted-vmcnt
// schedule (verified: conflicts 0). Cross-slot pipeline: kt==15's prefetch
// slots stage the NEXT slot's tile 0 (next A addrs from early per-thread
// tokmap loads -> vmcnt gate counts invariant: gates specify REMAINING ops).
// Last slot restages itself into the dead buffer (uniform code & counts).
// Ts removed from LDS (direct per-thread gathers); Gs via preloaded register.
__global__ __launch_bounds__(512, 2) void moe_ggemm_kernel(
    const unsigned short* __restrict__ Xb, const unsigned short* __restrict__ Wt,
    const unsigned int* __restrict__ table, const unsigned int* __restrict__ total,
    const unsigned int* __restrict__ tokmap, const float* __restrict__ gpos,
    unsigned short* __restrict__ Y) {
  __shared__ unsigned short As[2][256][64];  // 64 KiB
  __shared__ unsigned short Bs[2][256][64];  // 64 KiB
  __shared__ float Gs[256];
  __shared__ unsigned int Stab[MAXB256];

  const int tid = threadIdx.x;
  const unsigned tot = *total;
  if (tid < MAXB256) Stab[tid] = table[tid];
  __syncthreads();

  const unsigned nwg = tot * 4u;
  const unsigned bx = blockIdx.x;
  const unsigned xcd = bx & 7u;
  const unsigned jj = bx >> 3;
  const unsigned chunk = (nwg + 7u) >> 3;
  const unsigned wbeg = xcd * chunk + jj;
  unsigned wend = (xcd + 1u) * chunk;
  if (wend > nwg) wend = nwg;
  if (wbeg >= wend) return;

  const int wv = tid >> 6;
  const int lane = tid & 63;
  const int lm = lane & 15;
  const int quad = lane >> 4;
  const int wvm = wv >> 2;            // 0..1
  const int woff_m = wvm * 128;
  const int woff_n = (wv & 3) * 64;
  const int srow = tid >> 3;                          // 0..63
  const int scol = ((tid & 7) ^ (srow & 7)) << 4;     // pre-swizzled source col
  const int rsw = (lm & 7) << 4;
  const int roff0 = (quad * 16) ^ rsw;
  const int roff1 = (64 + quad * 16) ^ rsw;
  char* const Ab = (char*)&As[0][0][0];
  char* const Bb = (char*)&Bs[0][0][0];
  const int sdst = wv * 8 * 128;

  // ---- current-slot meta (first w) ----
  unsigned w = wbeg;
  unsigned ent = Stab[w >> 2];
  int half = (int)((ent >> 23) & 1u);
  int row0 = (int)(ent & 0x7FFFFFu);
  int n0 = (int)(w & 3u) * 256;
  const char* pA[4];
  const char* pB[4];
  {
    const int e = (int)(ent >> 24);
#pragma unroll
    for (int i = 0; i < 4; ++i) {
      const int r = i * 64 + srow;
      const int rc = (half && r >= 128) ? 127 : r;
      pA[i] = (const char*)Xb + (size_t)tokmap[row0 + rc] * (HID * 2) + scol;
      pB[i] = (const char*)Wt + (size_t)e * (HID * HID * 2) +
              (size_t)(n0 + i * 64 + srow) * (HID * 2) + scol;
    }
  }
  if (tid < 256)
    Gs[tid] = gpos[row0 + ((half && tid >= 128) ? 127 : tid)];
  __syncthreads();

  // ---- prologue: stage tile 0 -> buf0, order A0,A2,B0..B3,A1,A3 ----
  load_lds16(pA[0], Ab + 0 * 8192 + sdst);
  load_lds16(pA[2], Ab + 2 * 8192 + sdst);
  load_lds16(pB[0], Bb + 0 * 8192 + sdst);
  load_lds16(pB[1], Bb + 1 * 8192 + sdst);
  load_lds16(pB[2], Bb + 2 * 8192 + sdst);
  load_lds16(pB[3], Bb + 3 * 8192 + sdst);
  load_lds16(pA[1], Ab + 1 * 8192 + sdst);
  load_lds16(pA[3], Ab + 3 * 8192 + sdst);

  f32x4 acc[8][4];
#pragma unroll
  for (int f = 0; f < 8; ++f)
#pragma unroll
    for (int g = 0; g < 4; ++g) acc[f][g] = (f32x4){0.f, 0.f, 0.f, 0.f};

  asm volatile("s_waitcnt vmcnt(2)" ::: "memory");
  __builtin_amdgcn_s_barrier();

  while (true) {
    // ---- next-slot meta + early address gathers (issued before the K loop:
    // they complete during kt 0-1 and drop out of the vmcnt queue) ----
    const unsigned wn = (w + 32u < wend) ? w + 32u : w;
    const unsigned ent2 = Stab[wn >> 2];
    const int half2 = (int)((ent2 >> 23) & 1u);
    const int row02 = (int)(ent2 & 0x7FFFFFu);
    const int n02 = (int)(wn & 3u) * 256;
    const char* nA[4];
    const char* nB[4];
    {
      const int e2 = (int)(ent2 >> 24);
#pragma unroll
      for (int i = 0; i < 4; ++i) {
        const int r = i * 64 + srow;
        const int rc = (half2 && r >= 128) ? 127 : r;
        nA[i] = (const char*)Xb + (size_t)tokmap[row02 + rc] * (HID * 2) + scol;
        nB[i] = (const char*)Wt + (size_t)e2 * (HID * HID * 2) +
                (size_t)(n02 + i * 64 + srow) * (HID * 2) + scol;
      }
    }
    float g2val = 0.f;
    if (tid < 256)
      g2val = gpos[row02 + ((half2 && tid >= 128) ? 127 : tid)];

    for (int kt = 0; kt < NT; ++kt) {
      const int c = kt & 1;
      const char* ab = Ab + c * 32768;
      const char* bb = Bb + c * 32768;
      char* const ast = Ab + (c ^ 1) * 32768;
      char* const bst = Bb + (c ^ 1) * 32768;

      // stage sources: tiles 1..15 of current slot, then next slot's tile 0
      const char *sA0, *sA1, *sA2, *sA3, *sB0, *sB1, *sB2, *sB3;
      if (kt < NT - 1) {
        const int koff = (kt + 1) * 128;
        sA0 = pA[0] + koff; sA1 = pA[1] + koff;
        sA2 = pA[2] + koff; sA3 = pA[3] + koff;
        sB0 = pB[0] + koff; sB1 = pB[1] + koff;
        sB2 = pB[2] + koff; sB3 = pB[3] + koff;
      } else {
        sA0 = nA[0]; sA1 = nA[1]; sA2 = nA[2]; sA3 = nA[3];
        sB0 = nB[0]; sB1 = nB[1]; sB2 = nB[2]; sB3 = nB[3];
      }

      bf16x8 a[4][2], b[4][2];

      // -------- P0: read a(f0-3), b(g0-1); stage A0,A2
#pragma unroll
      for (int f = 0; f < 4; ++f) {
        const char* rp = ab + (woff_m + 16 * f + lm) * 128;
        a[f][0] = *(const bf16x8*)(rp + roff0);
        a[f][1] = *(const bf16x8*)(rp + roff1);
      }
#pragma unroll
      for (int g = 0; g < 2; ++g) {
        const char* rp = bb + (woff_n + 16 * g + lm) * 128;
        b[g][0] = *(const bf16x8*)(rp + roff0);
        b[g][1] = *(const bf16x8*)(rp + roff1);
      }
      load_lds16(sA0, ast + 0 * 8192 + sdst);
      load_lds16(sA2, ast + 2 * 8192 + sdst);
      __builtin_amdgcn_s_barrier();
      asm volatile("s_waitcnt lgkmcnt(0)" ::: "memory");
      __builtin_amdgcn_s_setprio(1);
#pragma unroll
      for (int f = 0; f < 4; ++f)
#pragma unroll
        for (int g = 0; g < 2; ++g) {
          acc[f][g] = __builtin_amdgcn_mfma_f32_16x16x32_bf16(a[f][0], b[g][0], acc[f][g], 0, 0, 0);
          acc[f][g] = __builtin_amdgcn_mfma_f32_16x16x32_bf16(a[f][1], b[g][1], acc[f][g], 0, 0, 0);
        }
      __builtin_amdgcn_s_setprio(0);
      __builtin_amdgcn_s_barrier();

      // -------- P1: read b(g2-3); stage B0,B1; gate vmcnt(4)
#pragma unroll
      for (int g = 2; g < 4; ++g) {
        const char* rp = bb + (woff_n + 16 * g + lm) * 128;
        b[g][0] = *(const bf16x8*)(rp + roff0);
        b[g][1] = *(const bf16x8*)(rp + roff1);
      }
      load_lds16(sB0, bst + 0 * 8192 + sdst);
      load_lds16(sB1, bst + 1 * 8192 + sdst);
      __builtin_amdgcn_s_barrier();
      asm volatile("s_waitcnt lgkmcnt(0)" ::: "memory");
      __builtin_amdgcn_s_setprio(1);
#pragma unroll
      for (int f = 0; f < 4; ++f)
#pragma unroll
        for (int g = 2; g < 4; ++g) {
          acc[f][g] = __builtin_amdgcn_mfma_f32_16x16x32_bf16(a[f][0], b[g][0], acc[f][g], 0, 0, 0);
          acc[f][g] = __builtin_amdgcn_mfma_f32_16x16x32_bf16(a[f][1], b[g][1], acc[f][g], 0, 0, 0);
        }
      __builtin_amdgcn_s_setprio(0);
      asm volatile("s_waitcnt vmcnt(4)" ::: "memory");
      __builtin_amdgcn_s_barrier();

      // -------- P2: read a(f4-7); stage B2,B3
#pragma unroll
      for (int f = 0; f < 4; ++f) {
        const char* rp = ab + (woff_m + 16 * (f + 4) + lm) * 128;
        a[f][0] = *(const bf16x8*)(rp + roff0);
        a[f][1] = *(const bf16x8*)(rp + roff1);
      }
      load_lds16(sB2, bst + 2 * 8192 + sdst);
      load_lds16(sB3, bst + 3 * 8192 + sdst);
      __builtin_amdgcn_s_barrier();
      asm volatile("s_waitcnt lgkmcnt(0)" ::: "memory");
      __builtin_amdgcn_s_setprio(1);
#pragma unroll
      for (int f = 0; f < 4; ++f)
#pragma unroll
        for (int g = 2; g < 4; ++g) {
          acc[f + 4][g] = __builtin_amdgcn_mfma_f32_16x16x32_bf16(a[f][0], b[g][0], acc[f + 4][g], 0, 0, 0);
          acc[f + 4][g] = __builtin_amdgcn_mfma_f32_16x16x32_bf16(a[f][1], b[g][1], acc[f + 4][g], 0, 0, 0);
        }
      __builtin_amdgcn_s_setprio(0);
      __builtin_amdgcn_s_barrier();

      // -------- P3: stage A1,A3; mfma f4-7 x g0-1; gate vmcnt(2)
      load_lds16(sA1, ast + 1 * 8192 + sdst);
      load_lds16(sA3, ast + 3 * 8192 + sdst);
      __builtin_amdgcn_s_barrier();
      __builtin_amdgcn_s_setprio(1);
#pragma unroll
      for (int f = 0; f < 4; ++f)
#pragma unroll
        for (int g = 0; g < 2; ++g) {
          acc[f + 4][g] = __builtin_amdgcn_mfma_f32_16x16x32_bf16(a[f][0], b[g][0], acc[f + 4][g], 0, 0, 0);
          acc[f + 4][g] = __builtin_amdgcn_mfma_f32_16x16x32_bf16(a[f][1], b[g][1], acc[f + 4][g], 0, 0, 0);
        }
      __builtin_amdgcn_s_setprio(0);
      asm volatile("s_waitcnt vmcnt(2)" ::: "memory");
      __builtin_amdgcn_s_barrier();
    }

    // ---- epilogue: next tile-0 stages (A1n,A3n) stay in flight ----
    if (!(half && wvm)) {
#pragma unroll
      for (int f = 0; f < 8; ++f)
#pragma unroll
        for (int r = 0; r < 4; ++r) {
          const int row = woff_m + 16 * f + quad * 4 + r;
          const float gte = Gs[row];
          unsigned short* yrow = Y + (size_t)(row0 + row) * HID + n0;
#pragma unroll
          for (int g = 0; g < 4; ++g)
            yrow[woff_n + 16 * g + lm] = (unsigned short)f2bf_rne(gte * acc[f][g][r]);
        }
    }
    __syncthreads();                 // all Gs reads done
    if (tid < 256) Gs[tid] = g2val;  // ds_write from preloaded reg (no drain)
    if (wn == w) break;

    // advance to next slot
    w = wn;
    half = half2;
    row0 = row02;
    n0 = n02;
#pragma unroll
    for (int i = 0; i < 4; ++i) { pA[i] = nA[i]; pB[i] = nB[i]; }
#pragma unroll
    for (int f = 0; f < 8; ++f)
#pragma unroll
      for (int g = 0; g < 4; ++g) acc[f][g] = (f32x4){0.f, 0.f, 0.f, 0.f};
  }

  asm volatile("s_waitcnt vmcnt(0)" ::: "memory");
}

// reduce: out[t,:] = sum_k Y[inv[t,k],:] + eps[t].  2 tokens/block.
__global__ __launch_bounds__(256) void reduce_kernel(
    const unsigned short* __restrict__ Y, const unsigned int* __restrict__ inv,
    const float* __restrict__ epst, float* __restrict__ out) {
  const int sub = threadIdx.x >> 7;
  const int ct = threadIdx.x & 127;
  const int t = blockIdx.x * 2 + sub;
  const int c0 = ct * 8;

  float s[8];
  const float ep = epst[t];
#pragma unroll
  for (int i = 0; i < 8; ++i) s[i] = ep;

#pragma unroll
  for (int k = 0; k < TOPK; ++k) {
    const unsigned pos = inv[(size_t)t * TOPK + k];
    const uint4 v = *(const uint4*)(Y + (size_t)pos * HID + c0);
    s[0] += bfbits2f(v.x & 0xFFFFu);
    s[1] += bfbits2f(v.x >> 16);
    s[2] += bfbits2f(v.y & 0xFFFFu);
    s[3] += bfbits2f(v.y >> 16);
    s[4] += bfbits2f(v.z & 0xFFFFu);
    s[5] += bfbits2f(v.z >> 16);
    s[6] += bfbits2f(v.w & 0xFFFFu);
    s[7] += bfbits2f(v.w >> 16);
  }
  float* orow = out + (size_t)t * HID + c0;
  *(float4*)orow = (float4){s[0], s[1], s[2], s[3]};
  *(float4*)(orow + 4) = (float4){s[4], s[5], s[6], s[7]};
}

extern "C" void kernel_launch(void* const* d_in, const int* in_sizes, int n_in,
                              void* d_out, int out_size, void* d_ws, size_t ws_size,
                              hipStream_t stream) {
  const float* tokens = (const float*)d_in[0];  // [4,2048,1024] f32
  const float* rw = (const float*)d_in[1];      // [16,1024] f32
  const float* rb = (const float*)d_in[2];      // [16] f32
  const float* ew = (const float*)d_in[3];      // [16,1024,1024] f32
  float* out = (float*)d_out;                   // [4,2048,1024] f32

  char* ws = (char*)d_ws;
  const size_t OFF_XB = 0;                        // 16 MB
  const size_t OFF_WT = 16777216;                 // 32 MB
  const size_t OFF_Y = 50331648;                  // 100 MB (51200 x 1024 bf16)
  const size_t OFF_META = 155189248;
  const size_t M_TOKMAP = OFF_META + 0;           // 51200 u32
  const size_t M_GPOS = OFF_META + 204800;        // 51200 f32
  const size_t M_TOTAL = OFF_META + 409600;       // 1 u32 (pad 64)
  const size_t M_TABLE = OFF_META + 409664;       // 400 u32 (pad)
  const size_t M_INV = OFF_META + 411328;         // 49152 u32
  const size_t M_TOPK = OFF_META + 607936;        // 8192 u32
  const size_t M_G6 = OFF_META + 640704;          // 49152 f32
  const size_t M_EPST = OFF_META + 837312;        // 8192 f32

  unsigned short* Xb = (unsigned short*)(ws + OFF_XB);
  unsigned short* Wt = (unsigned short*)(ws + OFF_WT);
  unsigned short* Y = (unsigned short*)(ws + OFF_Y);
  unsigned int* tokmap = (unsigned int*)(ws + M_TOKMAP);
  float* gpos = (float*)(ws + M_GPOS);
  unsigned int* total = (unsigned int*)(ws + M_TOTAL);
  unsigned int* table = (unsigned int*)(ws + M_TABLE);
  unsigned int* inv = (unsigned int*)(ws + M_INV);
  unsigned int* topk = (unsigned int*)(ws + M_TOPK);
  float* g6 = (float*)(ws + M_G6);
  float* epst = (float*)(ws + M_EPST);

  fused_pre_kernel<<<dim3(ROUTER_BLKS + (HID / 64) * (HID / 64) * NE), dim3(256),
                     0, stream>>>(tokens, rw, rb, Xb, topk, g6, epst, ew, Wt);
  sortassign_kernel<<<dim3(NE), dim3(1024), 0, stream>>>(
      topk, g6, tokmap, gpos, inv, table, total);
  moe_ggemm_kernel<<<dim3(256), dim3(512), 0, stream>>>(
      Xb, Wt, table, total, tokmap, gpos, Y);
  reduce_kernel<<<dim3(NTOK / 2), dim3(256), 0, stream>>>(Y, inv, epst, out);
}